// Round 4
// baseline (212.119 us; speedup 1.0000x reference)
//
#include <hip/hip_runtime.h>

// KvPageState fused, wave-per-row, 2-launch:
//   out[slot] <- (valid(inv[slot]) ? [new_k[t], new_v[t]] : kv_pages[slot])
//
// Shapes (fp32):
//   kv_pages    [1024, 64, 16, 128] -> 65536 slot-rows of 2048 floats (8 KiB)
//   new_k/new_v [8192, 8, 128]      -> per-token 1024 floats each
//   token_dests i32[8192], flat slot in [0, 65536), -1/OOB = drop
//
// inv (d_ws) is NOT initialized: entry inv[slot]=t is accepted only if
// 0<=t<num_tokens AND dests[t]==slot. Arbitrary garbage either fails the
// check (-> copy from kv_pages, correct) or accidentally names the one token
// that genuinely targets this slot (-> identical output). Distinct dests
// make the scatter race-free. Saves the init launch + its traffic.
//
// Each 64-lane wave owns one 8 KiB slot-row per iteration (8x float4/lane).
// (inv, dests) for the NEXT row are prefetched so the 2-deep dependent
// chain hides under the current row's data movement. Loads nontemporal
// (pure streaming); stores regular (TCC write-combining, matches the
// 6.7-6.9 TB/s fill-kernel path).

typedef float f4 __attribute__((ext_vector_type(4)));

__global__ void inv_scatter_kernel(const int* __restrict__ dests, int num_tokens,
                                   int* __restrict__ inv, int num_slots) {
    const int t = blockIdx.x * blockDim.x + threadIdx.x;
    if (t >= num_tokens) return;
    const int d = dests[t];
    if (d >= 0 && d < num_slots) inv[d] = t;
}

__global__ void __launch_bounds__(256, 8)
fused_copy_scatter(const f4* __restrict__ kv_pages,
                   const f4* __restrict__ new_k,
                   const f4* __restrict__ new_v,
                   const int* __restrict__ inv,
                   const int* __restrict__ dests,
                   f4* __restrict__ out,
                   int num_slots, int num_tokens) {
    const int lane   = threadIdx.x & 63;
    const int wave   = blockIdx.x * (blockDim.x >> 6) + (threadIdx.x >> 6);
    const int nwaves = gridDim.x * (blockDim.x >> 6);

    int slot = wave;
    if (slot >= num_slots) return;

    int t  = inv[slot];                                            // wave-uniform
    int td = (t >= 0 && t < num_tokens) ? dests[t] : -1;           // validate

    for (; slot < num_slots; slot += nwaves) {
        // prefetch next row's (inv, dests) so the chain hides under the copy
        const int nslot = slot + nwaves;
        int tn = -1, tdn = -1;
        if (nslot < num_slots) {
            tn = inv[nslot];
            if (tn >= 0 && tn < num_tokens) tdn = dests[tn];
        }

        f4* o = out + (size_t)slot * 512 + lane;
        if (td == slot) {                                          // fresh row
            const f4* k = new_k + (size_t)t * 256 + lane;
            const f4* v = new_v + (size_t)t * 256 + lane;
#pragma unroll
            for (int j = 0; j < 4; ++j)
                o[j * 64] = __builtin_nontemporal_load(k + j * 64);
#pragma unroll
            for (int j = 0; j < 4; ++j)
                o[256 + j * 64] = __builtin_nontemporal_load(v + j * 64);
        } else {                                                   // keep row
            const f4* src = kv_pages + (size_t)slot * 512 + lane;
#pragma unroll
            for (int j = 0; j < 8; ++j)
                o[j * 64] = __builtin_nontemporal_load(src + j * 64);
        }
        t = tn; td = tdn;
    }
}

// Fallback (ws too small): plain copy + overwrite scatter.
__global__ void kv_scatter_kernel(const f4* __restrict__ new_k,
                                  const f4* __restrict__ new_v,
                                  const int* __restrict__ dests,
                                  f4* __restrict__ out,
                                  int num_slots) {
    const int t = blockIdx.x;
    const int d = dests[t];
    if (d < 0 || d >= num_slots) return;
    const f4* k = new_k + (size_t)t * 256;
    const f4* v = new_v + (size_t)t * 256;
    f4* o = out + (size_t)d * 512;
    const int i = threadIdx.x;
    o[i]       = k[i];
    o[i + 256] = v[i];
}

extern "C" void kernel_launch(void* const* d_in, const int* in_sizes, int n_in,
                              void* d_out, int out_size, void* d_ws, size_t ws_size,
                              hipStream_t stream) {
    const float* kv_pages = (const float*)d_in[0];
    const float* new_k    = (const float*)d_in[1];
    const float* new_v    = (const float*)d_in[2];
    const int*   dests    = (const int*)d_in[3];

    const int num_tokens = in_sizes[3];                 // 8192
    const int row_floats = 2 * 8 * 128;                 // 2048
    const int num_slots  = out_size / row_floats;       // 65536

    if (ws_size >= (size_t)num_slots * sizeof(int)) {
        int* inv = (int*)d_ws;
        inv_scatter_kernel<<<(num_tokens + 255) / 256, 256, 0, stream>>>(
            dests, num_tokens, inv, num_slots);
        // 2048 blocks x 256 thr = 8192 waves, fully resident (8 blk/CU);
        // 65536/8192 = 8 rows per wave.
        fused_copy_scatter<<<2048, 256, 0, stream>>>(
            (const f4*)kv_pages, (const f4*)new_k, (const f4*)new_v,
            inv, dests, (f4*)d_out, num_slots, num_tokens);
    } else {
        hipMemcpyAsync(d_out, kv_pages, (size_t)out_size * sizeof(float),
                       hipMemcpyDeviceToDevice, stream);
        kv_scatter_kernel<<<num_tokens, 256, 0, stream>>>(
            (const f4*)new_k, (const f4*)new_v, dests, (f4*)d_out, num_slots);
    }
}

// Round 5
// 198.151 us; speedup vs baseline: 1.0705x; 1.0705x over previous
//
#include <hip/hip_runtime.h>

// KvPageState fused, wave-per-row, 2-launch, nontemporal both ways:
//   out[slot] <- (valid(inv[slot]) ? [new_k[t], new_v[t]] : kv_pages[slot])
//
// Shapes (fp32):
//   kv_pages    [1024, 64, 16, 128] -> 65536 slot-rows of 2048 floats (8 KiB)
//   new_k/new_v [8192, 8, 128]      -> per-token 1024 floats each
//   token_dests i32[8192], flat slot in [0, 65536), -1/OOB = drop
//
// inv (d_ws) is NOT initialized: entry inv[slot]=t is accepted only if
// 0<=t<num_tokens AND dests[t]==slot. Garbage either fails the check
// (-> copy kv_pages, correct) or names the one token genuinely targeting
// this slot (-> identical row). Distinct dests -> race-free.
//
// R4 post-mortem: regular stores regressed 197->212 us (write allocations
// contend with the streaming read side in L2). Nontemporal restored on
// BOTH loads and stores; this kernel is R3 + dropped-init, single diff
// vs R4 for clean attribution.

typedef float f4 __attribute__((ext_vector_type(4)));

__global__ void inv_scatter_kernel(const int* __restrict__ dests, int num_tokens,
                                   int* __restrict__ inv, int num_slots) {
    const int t = blockIdx.x * blockDim.x + threadIdx.x;
    if (t >= num_tokens) return;
    const int d = dests[t];
    if (d >= 0 && d < num_slots) inv[d] = t;
}

__global__ void __launch_bounds__(256, 8)
fused_copy_scatter(const f4* __restrict__ kv_pages,
                   const f4* __restrict__ new_k,
                   const f4* __restrict__ new_v,
                   const int* __restrict__ inv,
                   const int* __restrict__ dests,
                   f4* __restrict__ out,
                   int num_slots, int num_tokens) {
    const int lane   = threadIdx.x & 63;
    const int wave   = blockIdx.x * (blockDim.x >> 6) + (threadIdx.x >> 6);
    const int nwaves = gridDim.x * (blockDim.x >> 6);

    int slot = wave;
    if (slot >= num_slots) return;

    int t  = inv[slot];                                            // wave-uniform
    int td = (t >= 0 && t < num_tokens) ? dests[t] : -1;           // validate

    for (; slot < num_slots; slot += nwaves) {
        // prefetch next row's (inv, dests): chain hides under the copy
        const int nslot = slot + nwaves;
        int tn = -1, tdn = -1;
        if (nslot < num_slots) {
            tn = inv[nslot];
            if (tn >= 0 && tn < num_tokens) tdn = dests[tn];
        }

        f4* o = out + (size_t)slot * 512 + lane;
        if (td == slot) {                                          // fresh row
            const f4* k = new_k + (size_t)t * 256 + lane;
            const f4* v = new_v + (size_t)t * 256 + lane;
#pragma unroll
            for (int j = 0; j < 4; ++j)
                __builtin_nontemporal_store(__builtin_nontemporal_load(k + j * 64), o + j * 64);
#pragma unroll
            for (int j = 0; j < 4; ++j)
                __builtin_nontemporal_store(__builtin_nontemporal_load(v + j * 64), o + 256 + j * 64);
        } else {                                                   // keep row
            const f4* src = kv_pages + (size_t)slot * 512 + lane;
#pragma unroll
            for (int j = 0; j < 8; ++j)
                __builtin_nontemporal_store(__builtin_nontemporal_load(src + j * 64), o + j * 64);
        }
        t = tn; td = tdn;
    }
}

// Fallback (ws too small): plain copy + overwrite scatter.
__global__ void kv_scatter_kernel(const f4* __restrict__ new_k,
                                  const f4* __restrict__ new_v,
                                  const int* __restrict__ dests,
                                  f4* __restrict__ out,
                                  int num_slots) {
    const int t = blockIdx.x;
    const int d = dests[t];
    if (d < 0 || d >= num_slots) return;
    const f4* k = new_k + (size_t)t * 256;
    const f4* v = new_v + (size_t)t * 256;
    f4* o = out + (size_t)d * 512;
    const int i = threadIdx.x;
    o[i]       = k[i];
    o[i + 256] = v[i];
}

extern "C" void kernel_launch(void* const* d_in, const int* in_sizes, int n_in,
                              void* d_out, int out_size, void* d_ws, size_t ws_size,
                              hipStream_t stream) {
    const float* kv_pages = (const float*)d_in[0];
    const float* new_k    = (const float*)d_in[1];
    const float* new_v    = (const float*)d_in[2];
    const int*   dests    = (const int*)d_in[3];

    const int num_tokens = in_sizes[3];                 // 8192
    const int row_floats = 2 * 8 * 128;                 // 2048
    const int num_slots  = out_size / row_floats;       // 65536

    if (ws_size >= (size_t)num_slots * sizeof(int)) {
        int* inv = (int*)d_ws;
        inv_scatter_kernel<<<(num_tokens + 255) / 256, 256, 0, stream>>>(
            dests, num_tokens, inv, num_slots);
        // 2048 blocks x 256 thr = 8192 waves, fully resident (8 blk/CU);
        // 65536/8192 = 8 rows per wave.
        fused_copy_scatter<<<2048, 256, 0, stream>>>(
            (const f4*)kv_pages, (const f4*)new_k, (const f4*)new_v,
            inv, dests, (f4*)d_out, num_slots, num_tokens);
    } else {
        hipMemcpyAsync(d_out, kv_pages, (size_t)out_size * sizeof(float),
                       hipMemcpyDeviceToDevice, stream);
        kv_scatter_kernel<<<num_tokens, 256, 0, stream>>>(
            (const f4*)new_k, (const f4*)new_v, dests, (f4*)d_out, num_slots);
    }
}